// Round 9
// baseline (227.074 us; speedup 1.0000x reference)
//
#include <hip/hip_runtime.h>
#include <stdint.h>

#define NN 8192
#define DD 512
#define SPLIT 4
#define ITERS_PER_SPLIT 16   // 64 total K-iters of 128 / SPLIT

typedef uint16_t u16;
typedef __bf16 bf16x8_t __attribute__((ext_vector_type(8)));
typedef float f32x4_t __attribute__((ext_vector_type(4)));
typedef uint32_t u32x4_t __attribute__((ext_vector_type(4)));

__device__ __forceinline__ u16 f2bf(float x) {
  uint32_t u = __builtin_bit_cast(uint32_t, x);
  u += 0x7FFFu + ((u >> 16) & 1u);   // round-to-nearest-even
  return (u16)(u >> 16);
}
__device__ __forceinline__ float h2f(uint32_t bits) {
  return (float)__builtin_bit_cast(_Float16, (u16)bits);
}

__device__ __forceinline__ unsigned encf(float f) {
  unsigned u = __builtin_bit_cast(unsigned, f);
  return (u & 0x80000000u) ? ~u : (u | 0x80000000u);
}
__device__ __forceinline__ float decf(unsigned e) {
  unsigned u = (e & 0x80000000u) ? (e & 0x7FFFFFFFu) : ~e;
  return __builtin_bit_cast(float, u);
}

// ---------------------------------------------------------------- W[k][n] -> WT[n][k] bf16, init maxenc
__global__ __launch_bounds__(256) void k_convert_W(const float* __restrict__ W,
                                                   u16* __restrict__ WT,
                                                   unsigned* __restrict__ maxenc) {
  int t = blockIdx.x * blockDim.x + threadIdx.x;  // 32768 threads
  if (t == 0) *maxenc = 0u;
  int n = t >> 6;
  int k8 = (t & 63) << 3;
  u16 tmp[8];
#pragma unroll
  for (int j = 0; j < 8; ++j) tmp[j] = f2bf(W[(size_t)(k8 + j) * DD + n]);
  uint32_t w0 = (uint32_t)tmp[0] | ((uint32_t)tmp[1] << 16);
  uint32_t w1 = (uint32_t)tmp[2] | ((uint32_t)tmp[3] << 16);
  uint32_t w2 = (uint32_t)tmp[4] | ((uint32_t)tmp[5] << 16);
  uint32_t w3 = (uint32_t)tmp[6] | ((uint32_t)tmp[7] << 16);
  *(uint4*)&WT[(size_t)n * DD + k8] = make_uint4(w0, w1, w2, w3);
}

// ---------------------------------------------------------------- h = input @ W  (bf16 MFMA)
__global__ __launch_bounds__(256) void k_gemm_h(const float* __restrict__ Af,
                                                const u16* __restrict__ BT,
                                                u16* __restrict__ HT,
                                                const float* __restrict__ a1,
                                                const float* __restrict__ a2,
                                                float* __restrict__ e1part,
                                                float* __restrict__ e2part) {
  __shared__ __align__(16) u16 As[128 * 32];
  __shared__ __align__(16) u16 Bs[128 * 32];
  const int tid = threadIdx.x;
  const int wid = tid >> 6, lane = tid & 63;
  const int wr = wid >> 1, wc = wid & 1;
  const int lr = lane & 15, kg = lane >> 4;
  const int rowBase = blockIdx.x * 128;
  const int colBase = blockIdx.y * 128;
  const int sr = tid >> 2, sc = tid & 3;
  f32x4_t acc[4][4] = {};
  for (int kt = 0; kt < 16; ++kt) {
    const int k0 = kt * 32 + sc * 8;
    {
      float4 f0 = *(const float4*)&Af[(size_t)(rowBase + sr) * DD + k0];
      float4 f1 = *(const float4*)&Af[(size_t)(rowBase + sr) * DD + k0 + 4];
      *(uint4*)&As[tid * 8] = make_uint4(
          (uint32_t)f2bf(f0.x) | ((uint32_t)f2bf(f0.y) << 16),
          (uint32_t)f2bf(f0.z) | ((uint32_t)f2bf(f0.w) << 16),
          (uint32_t)f2bf(f1.x) | ((uint32_t)f2bf(f1.y) << 16),
          (uint32_t)f2bf(f1.z) | ((uint32_t)f2bf(f1.w) << 16));
      float4 g0 = *(const float4*)&Af[(size_t)(rowBase + 64 + sr) * DD + k0];
      float4 g1 = *(const float4*)&Af[(size_t)(rowBase + 64 + sr) * DD + k0 + 4];
      *(uint4*)&As[(tid + 256) * 8] = make_uint4(
          (uint32_t)f2bf(g0.x) | ((uint32_t)f2bf(g0.y) << 16),
          (uint32_t)f2bf(g0.z) | ((uint32_t)f2bf(g0.w) << 16),
          (uint32_t)f2bf(g1.x) | ((uint32_t)f2bf(g1.y) << 16),
          (uint32_t)f2bf(g1.z) | ((uint32_t)f2bf(g1.w) << 16));
    }
    *(uint4*)&Bs[tid * 8] = *(const uint4*)&BT[(size_t)(colBase + sr) * DD + k0];
    *(uint4*)&Bs[(tid + 256) * 8] = *(const uint4*)&BT[(size_t)(colBase + 64 + sr) * DD + k0];
    __syncthreads();
    bf16x8_t af[4], bfv[4];
#pragma unroll
    for (int mt = 0; mt < 4; ++mt)
      af[mt] = *(const bf16x8_t*)&As[(wr * 64 + mt * 16 + lr) * 32 + kg * 8];
#pragma unroll
    for (int nt = 0; nt < 4; ++nt)
      bfv[nt] = *(const bf16x8_t*)&Bs[(wc * 64 + nt * 16 + lr) * 32 + kg * 8];
#pragma unroll
    for (int mt = 0; mt < 4; ++mt)
#pragma unroll
      for (int nt = 0; nt < 4; ++nt)
        acc[mt][nt] = __builtin_amdgcn_mfma_f32_16x16x32_bf16(af[mt], bfv[nt], acc[mt][nt], 0, 0, 0);
    __syncthreads();
  }
  float a1v[4], a2v[4];
#pragma unroll
  for (int nt = 0; nt < 4; ++nt) {
    const int col = colBase + wc * 64 + nt * 16 + lr;
    a1v[nt] = a1[col];
    a2v[nt] = a2[col];
  }
  const int cg = blockIdx.y * 2 + wc;  // 64-col group 0..7
#pragma unroll
  for (int mt = 0; mt < 4; ++mt) {
#pragma unroll
    for (int nt = 0; nt < 4; ++nt) {
      const int row0 = rowBase + wr * 64 + mt * 16 + kg * 4;
      const int col = colBase + wc * 64 + nt * 16 + lr;
      uint32_t lo = (uint32_t)f2bf(acc[mt][nt][0]) | ((uint32_t)f2bf(acc[mt][nt][1]) << 16);
      uint32_t hi = (uint32_t)f2bf(acc[mt][nt][2]) | ((uint32_t)f2bf(acc[mt][nt][3]) << 16);
      *(uint2*)&HT[(size_t)col * NN + row0] = make_uint2(lo, hi);
    }
#pragma unroll
    for (int r = 0; r < 4; ++r) {
      float t1 = 0.f, t2 = 0.f;
#pragma unroll
      for (int nt = 0; nt < 4; ++nt) {
        t1 += acc[mt][nt][r] * a1v[nt];
        t2 += acc[mt][nt][r] * a2v[nt];
      }
#pragma unroll
      for (int m = 1; m <= 8; m <<= 1) {
        t1 += __shfl_xor(t1, m);
        t2 += __shfl_xor(t2, m);
      }
      if (lr == 0) {
        const int row = rowBase + wr * 64 + mt * 16 + kg * 4 + r;
        e1part[(size_t)cg * NN + row] = t1;
        e2part[(size_t)cg * NN + row] = t2;
      }
    }
  }
}

// ---------------------------------------------------------------- reduce e1/e2 slices, maxE2
__global__ __launch_bounds__(256) void k_e12small(const float* __restrict__ e1part,
                                                  const float* __restrict__ e2part,
                                                  float* __restrict__ e1, float* __restrict__ e2,
                                                  unsigned* __restrict__ maxenc) {
  const int row = blockIdx.x * 256 + threadIdx.x;
  float s1 = 0.f, s2 = 0.f;
#pragma unroll
  for (int cg = 0; cg < 8; ++cg) {
    s1 += e1part[(size_t)cg * NN + row];
    s2 += e2part[(size_t)cg * NN + row];
  }
  e1[row] = s1;
  e2[row] = s2;
  atomicMax(maxenc, encf(s2));
}

// ---------------------------------------------------------------- fused masked-softmax @ h (split-K partials)
// 256 blocks (XCD-swizzled, 1/CU) x 1024 threads. Block owns 128 rows x 2048 K-cols.
// R8->R9: cross-iteration software pipeline — in each barrier-to-barrier region, the MFMAs
// on P[t] (matrix+LDS pipes) are interleaved with BUILDING P[t+1] (adj->exp VALU + ds_write
// to the other buffer). Race-free: buffer (t+1)&1 was last read before the previous barrier.
// adj(t+1) issues right after the barrier (consumed after ks=0's MFMAs); B ks=0 of t+1
// preloads before the raw barrier (vmcnt stays in flight).
__global__ __launch_bounds__(1024) void k_fused(const float* __restrict__ adj,
                                                const u16* __restrict__ HT,
                                                const float* __restrict__ e1,
                                                const float* __restrict__ e2,
                                                const unsigned* __restrict__ maxenc,
                                                u16* __restrict__ numpart,
                                                float* __restrict__ denpart) {
  __shared__ __align__(16) u16 P[2][128 * 128];       // 64KB double-buffered
  __shared__ __align__(16) float e2s[256 * 12];       // 12KB, stride-12 conflict-free
  __shared__ float partsum[2048];                     // 8KB
  const int tid = threadIdx.x;
  const int wid = tid >> 6;        // 0..15
  const int lane = tid & 63;
  const int lr = lane & 15;
  const int kg = lane >> 4;
  const int b = blockIdx.x;
  const int xcd = b & 7;
  const int bz = xcd >> 1;                           // 0..3, fixed per XCD
  const int rowBlock = (b >> 3) + ((xcd & 1) << 5);  // 0..63, bijective
  const int rowBase = rowBlock * 128;
  const int kk0 = bz * ITERS_PER_SPLIT;
  const int c = (tid >> 4) & 15;   // 8-col k-chunk within 128-tile
  const int m = tid & 15;
  const int mt0 = tid >> 8;        // 0..3
  const int r0l = mt0 * 16 + m;    // local rows r0l (0..63) and r0l+64
  const float e1r0 = e1[rowBase + r0l];
  const float e1r1 = e1[rowBase + r0l + 64];
  const float mE2 = decf(*maxenc);
  const float xb0 = e1r0 + mE2, xb1 = e1r1 + mE2;
  const float bnd0 = fmaxf(xb0, 0.2f * xb0);  // leakyrelu(e1+maxE2) >= all row scores
  const float bnd1 = fmaxf(xb1, 0.2f * xb1);
  {
    const float* e2g = e2 + kk0 * 128;
    if (tid < 256) {
      float4 u0 = *(const float4*)(e2g + tid * 8);
      float4 u1 = *(const float4*)(e2g + tid * 8 + 4);
      *(float4*)&e2s[tid * 12] = u0;
      *(float4*)&e2s[tid * 12 + 4] = u1;
    }
  }
  const float* adjp0 = adj + (size_t)(rowBase + r0l) * NN + c * 8;
  const float* adjp1 = adjp0 + (size_t)64 * NN;
  const int n0 = wid * 32;
  const u16* btp0 = HT + (size_t)(n0 + 0 + lr) * NN + kg * 8;
  const u16* btp1 = HT + (size_t)(n0 + 16 + lr) * NN + kg * 8;
  float dsum0 = 0.f, dsum1 = 0.f;
  f32x4_t acc[8][2] = {};
  // adj regs (single set, distance-1: loaded in iter t, consumed building P[t+1] mid-iter t)
  f32x4_t a00 = __builtin_nontemporal_load((const f32x4_t*)(adjp0 + kk0 * 128));
  f32x4_t a01 = __builtin_nontemporal_load((const f32x4_t*)(adjp0 + kk0 * 128 + 4));
  f32x4_t a10 = __builtin_nontemporal_load((const f32x4_t*)(adjp1 + kk0 * 128));
  f32x4_t a11 = __builtin_nontemporal_load((const f32x4_t*)(adjp1 + kk0 * 128 + 4));
  __syncthreads();  // e2s ready

// build one 8-col slab of P for iteration tt into buffer qb (rows slab SL: 0 -> r0l, 1 -> r0l+64)
#define BUILD_SLAB(tt, qb, SL)                                                              \
  {                                                                                         \
    const float* eg_ = &e2s[((tt) * 16 + c) * 12];                                          \
    f32x4_t ev0_ = *(const f32x4_t*)eg_;                                                    \
    f32x4_t ev1_ = *(const f32x4_t*)(eg_ + 4);                                              \
    float ee_[8] = {ev0_[0], ev0_[1], ev0_[2], ev0_[3], ev1_[0], ev1_[1], ev1_[2], ev1_[3]};\
    float aa_[8];                                                                           \
    if (SL) { aa_[0]=a10[0];aa_[1]=a10[1];aa_[2]=a10[2];aa_[3]=a10[3];                      \
              aa_[4]=a11[0];aa_[5]=a11[1];aa_[6]=a11[2];aa_[7]=a11[3]; }                    \
    else    { aa_[0]=a00[0];aa_[1]=a00[1];aa_[2]=a00[2];aa_[3]=a00[3];                      \
              aa_[4]=a01[0];aa_[5]=a01[1];aa_[6]=a01[2];aa_[7]=a01[3]; }                    \
    const float e1r_ = SL ? e1r1 : e1r0;                                                    \
    const float bnd_ = SL ? bnd1 : bnd0;                                                    \
    float pv_[8];                                                                           \
    _Pragma("unroll")                                                                       \
    for (int j = 0; j < 8; ++j) {                                                           \
      float x_ = e1r_ + ee_[j];                                                             \
      float s_ = fmaxf(x_, 0.2f * x_);                                                      \
      float p_ = (aa_[j] > -1e19f) ? __expf(s_ - bnd_) : 0.f;                               \
      pv_[j] = p_;                                                                          \
      if (SL) dsum1 += p_; else dsum0 += p_;                                                \
    }                                                                                       \
    uint32_t w0_ = (uint32_t)f2bf(pv_[0]) | ((uint32_t)f2bf(pv_[1]) << 16);                 \
    uint32_t w1_ = (uint32_t)f2bf(pv_[2]) | ((uint32_t)f2bf(pv_[3]) << 16);                 \
    uint32_t w2_ = (uint32_t)f2bf(pv_[4]) | ((uint32_t)f2bf(pv_[5]) << 16);                 \
    uint32_t w3_ = (uint32_t)f2bf(pv_[6]) | ((uint32_t)f2bf(pv_[7]) << 16);                 \
    *(uint4*)&(qb)[(tid + (SL ? 1024 : 0)) * 8] = make_uint4(w0_, w1_, w2_, w3_);           \
  }

  // prologue: build P[0] from prefetched adj(kk0)
  BUILD_SLAB(0, P[0], 0)
  BUILD_SLAB(0, P[0], 1)
  // preload B ks=0 for t=0 (in flight across barrier)
  bf16x8_t bc0 = *(const bf16x8_t*)(btp0 + kk0 * 128);
  bf16x8_t bc1 = *(const bf16x8_t*)(btp1 + kk0 * 128);
  asm volatile("s_waitcnt lgkmcnt(0)" ::: "memory");
  __builtin_amdgcn_s_barrier();

  for (int t = 0; t < ITERS_PER_SPLIT; ++t) {
    const int colBase = (kk0 + t) * 128;
    const u16* pb = &P[t & 1][0];
    u16* qb = &P[(t + 1) & 1][0];
    const bool more = (t + 1 < ITERS_PER_SPLIT);
    // issue adj(t+1) loads now; consumed after ks=0's MFMAs (~1.2K cy later)
    if (more) {
      const float* q0 = adjp0 + colBase + 128;
      const float* q1 = adjp1 + colBase + 128;
      a00 = __builtin_nontemporal_load((const f32x4_t*)q0);
      a01 = __builtin_nontemporal_load((const f32x4_t*)(q0 + 4));
      a10 = __builtin_nontemporal_load((const f32x4_t*)q1);
      a11 = __builtin_nontemporal_load((const f32x4_t*)(q1 + 4));
    }
    bf16x8_t bn0, bn1;
    // ---- ks=0 ----
    bn0 = *(const bf16x8_t*)(btp0 + colBase + 32);
    bn1 = *(const bf16x8_t*)(btp1 + colBase + 32);
#pragma unroll
    for (int mt = 0; mt < 8; ++mt) {
      bf16x8_t af = *(const bf16x8_t*)(pb + mt * 2048 + 0 * 512 + lane * 8);
      acc[mt][0] = __builtin_amdgcn_mfma_f32_16x16x32_bf16(af, bc0, acc[mt][0], 0, 0, 0);
      acc[mt][1] = __builtin_amdgcn_mfma_f32_16x16x32_bf16(af, bc1, acc[mt][1], 0, 0, 0);
    }
    bc0 = bn0; bc1 = bn1;
    if (more) BUILD_SLAB(t + 1, qb, 0)   // overlap with MFMA: VALU pipe
    // ---- ks=1 ----
    bn0 = *(const bf16x8_t*)(btp0 + colBase + 64);
    bn1 = *(const bf16x8_t*)(btp1 + colBase + 64);
#pragma unroll
    for (int mt = 0; mt < 8; ++mt) {
      bf16x8_t af = *(const bf16x8_t*)(pb + mt * 2048 + 1 * 512 + lane * 8);
      acc[mt][0] = __builtin_amdgcn_mfma_f32_16x16x32_bf16(af, bc0, acc[mt][0], 0, 0, 0);
      acc[mt][1] = __builtin_amdgcn_mfma_f32_16x16x32_bf16(af, bc1, acc[mt][1], 0, 0, 0);
    }
    bc0 = bn0; bc1 = bn1;
    if (more) BUILD_SLAB(t + 1, qb, 1)
    // ---- ks=2 ----
    bn0 = *(const bf16x8_t*)(btp0 + colBase + 96);
    bn1 = *(const bf16x8_t*)(btp1 + colBase + 96);
#pragma unroll
    for (int mt = 0; mt < 8; ++mt) {
      bf16x8_t af = *(const bf16x8_t*)(pb + mt * 2048 + 2 * 512 + lane * 8);
      acc[mt][0] = __builtin_amdgcn_mfma_f32_16x16x32_bf16(af, bc0, acc[mt][0], 0, 0, 0);
      acc[mt][1] = __builtin_amdgcn_mfma_f32_16x16x32_bf16(af, bc1, acc[mt][1], 0, 0, 0);
    }
    bc0 = bn0; bc1 = bn1;
    // ---- ks=3 ----
#pragma unroll
    for (int mt = 0; mt < 8; ++mt) {
      bf16x8_t af = *(const bf16x8_t*)(pb + mt * 2048 + 3 * 512 + lane * 8);
      acc[mt][0] = __builtin_amdgcn_mfma_f32_16x16x32_bf16(af, bc0, acc[mt][0], 0, 0, 0);
      acc[mt][1] = __builtin_amdgcn_mfma_f32_16x16x32_bf16(af, bc1, acc[mt][1], 0, 0, 0);
    }
    // preload B ks=0 for t+1 (in flight across barrier)
    if (more) {
      bc0 = *(const bf16x8_t*)(btp0 + colBase + 128);
      bc1 = *(const bf16x8_t*)(btp1 + colBase + 128);
    }
    asm volatile("s_waitcnt lgkmcnt(0)" ::: "memory");  // P[t+1] writes committed; vmcnt NOT drained
    __builtin_amdgcn_s_barrier();
  }
#undef BUILD_SLAB
  // deterministic per-row denominator reduction (16 partials per row, fixed order)
  partsum[tid] = dsum0;
  partsum[tid + 1024] = dsum1;
  __syncthreads();
  if (tid < 128) {
    const int rr = tid;
    const int rlo = rr & 63;
    const int off = (rr >> 6) << 10;  // +1024 for rows 64..127
    float s = 0.f;
#pragma unroll
    for (int cc = 0; cc < 16; ++cc)
      s += partsum[off + (rlo >> 4) * 256 + cc * 16 + (rlo & 15)];
    denpart[(size_t)bz * NN + rowBase + rr] = s;
  }
  u16* np = numpart + (size_t)bz * NN * DD;
#pragma unroll
  for (int mt = 0; mt < 8; ++mt)
#pragma unroll
    for (int nt = 0; nt < 2; ++nt)
#pragma unroll
      for (int r = 0; r < 4; ++r) {
        const int rowL = mt * 16 + kg * 4 + r;
        _Float16 hv = (_Float16)acc[mt][nt][r];
        __builtin_nontemporal_store(__builtin_bit_cast(u16, hv),
                                    &np[(size_t)(rowBase + rowL) * DD + n0 + nt * 16 + lr]);
      }
}

// ---------------------------------------------------------------- combine f16 partials: out = tanh(num/den)
__global__ __launch_bounds__(256) void k_combine(const u16* __restrict__ num,
                                                 const float* __restrict__ den,
                                                 float* __restrict__ out) {
  const size_t idx = (size_t)blockIdx.x * 256 + threadIdx.x;  // 8-half units
  const int row = (int)(idx >> 6);                            // 64 chunks of 8 per row
  float d = den[row] + den[NN + row] + den[2 * NN + row] + den[3 * NN + row];
  const u32x4_t* nv = (const u32x4_t*)num;
  const size_t stride = (size_t)NN * DD / 8;
  float s[8] = {};
#pragma unroll
  for (int sl = 0; sl < 4; ++sl) {
    u32x4_t q = __builtin_nontemporal_load(nv + sl * stride + idx);
    s[0] += h2f(q[0] & 0xffff); s[1] += h2f(q[0] >> 16);
    s[2] += h2f(q[1] & 0xffff); s[3] += h2f(q[1] >> 16);
    s[4] += h2f(q[2] & 0xffff); s[5] += h2f(q[2] >> 16);
    s[6] += h2f(q[3] & 0xffff); s[7] += h2f(q[3] >> 16);
  }
  const float inv = (d > 0.f) ? 1.f / d : 0.f;
  f32x4_t o0, o1;
#pragma unroll
  for (int j = 0; j < 4; ++j) o0[j] = 1.f - 2.f / (__expf(2.f * (s[j] * inv)) + 1.f);
#pragma unroll
  for (int j = 0; j < 4; ++j) o1[j] = 1.f - 2.f / (__expf(2.f * (s[4 + j] * inv)) + 1.f);
  __builtin_nontemporal_store(o0, ((f32x4_t*)out) + idx * 2);
  __builtin_nontemporal_store(o1, ((f32x4_t*)out) + idx * 2 + 1);
}

// ----------------------------------------------------------------
extern "C" void kernel_launch(void* const* d_in, const int* in_sizes, int n_in,
                              void* d_out, int out_size, void* d_ws, size_t ws_size,
                              hipStream_t stream) {
  const float* input = (const float*)d_in[0];
  const float* adj   = (const float*)d_in[1];
  const float* W     = (const float*)d_in[2];
  const float* a1    = (const float*)d_in[3];
  const float* a2    = (const float*)d_in[4];
  float* out = (float*)d_out;
  char* ws = (char*)d_ws;

  u16* hT        = (u16*)ws;                      // 8192*512*2  = 8,388,608
  float* e1      = (float*)(ws + 8388608);        // 32,768
  float* e2      = (float*)(ws + 8421376);        // 32,768
  unsigned* mx   = (unsigned*)(ws + 8454144);     // 4 (pad to 256)
  float* denp    = (float*)(ws + 8454400);        // SPLIT*8192*4 = 131,072
  float* e1p     = (float*)(ws + 8585472);        // 8*8192*4 = 262,144
  float* e2p     = (float*)(ws + 8847616);        // 262,144
  u16* nump      = (u16*)(ws + 9109760);          // SPLIT*8192*512*2 = 33,554,432
  // WT is dead before k_fused writes nump -> overlay:
  u16* WT        = (u16*)(ws + 9109760);          // 524,288

  hipLaunchKernelGGL(k_convert_W, dim3(128), dim3(256), 0, stream, W, WT, mx);
  hipLaunchKernelGGL(k_gemm_h, dim3(64, 4), dim3(256), 0, stream, input, WT, hT, a1, a2, e1p, e2p);
  hipLaunchKernelGGL(k_e12small, dim3(32), dim3(256), 0, stream, e1p, e2p, e1, e2, mx);
  hipLaunchKernelGGL(k_fused, dim3(64 * SPLIT), dim3(1024), 0, stream, adj, hT, e1, e2, mx, nump, denp);
  hipLaunchKernelGGL(k_combine, dim3(2048), dim3(256), 0, stream, nump, denp, out);
}

// Round 10
// 175.858 us; speedup vs baseline: 1.2912x; 1.2912x over previous
//
#include <hip/hip_runtime.h>
#include <stdint.h>

#define NN 8192
#define DD 512
#define SPLIT 4
#define ITERS_PER_SPLIT 16   // 64 total K-iters of 128 / SPLIT

typedef uint16_t u16;
typedef __bf16 bf16x8_t __attribute__((ext_vector_type(8)));
typedef float f32x4_t __attribute__((ext_vector_type(4)));
typedef uint32_t u32x4_t __attribute__((ext_vector_type(4)));

__device__ __forceinline__ u16 f2bf(float x) {
  uint32_t u = __builtin_bit_cast(uint32_t, x);
  u += 0x7FFFu + ((u >> 16) & 1u);   // round-to-nearest-even
  return (u16)(u >> 16);
}
__device__ __forceinline__ float h2f(uint32_t bits) {
  return (float)__builtin_bit_cast(_Float16, (u16)bits);
}

__device__ __forceinline__ unsigned encf(float f) {
  unsigned u = __builtin_bit_cast(unsigned, f);
  return (u & 0x80000000u) ? ~u : (u | 0x80000000u);
}
__device__ __forceinline__ float decf(unsigned e) {
  unsigned u = (e & 0x80000000u) ? (e & 0x7FFFFFFFu) : ~e;
  return __builtin_bit_cast(float, u);
}

// ---------------------------------------------------------------- W[k][n] -> WT[n][k] bf16, init maxenc
__global__ __launch_bounds__(256) void k_convert_W(const float* __restrict__ W,
                                                   u16* __restrict__ WT,
                                                   unsigned* __restrict__ maxenc) {
  int t = blockIdx.x * blockDim.x + threadIdx.x;  // 32768 threads
  if (t == 0) *maxenc = 0u;
  int n = t >> 6;
  int k8 = (t & 63) << 3;
  u16 tmp[8];
#pragma unroll
  for (int j = 0; j < 8; ++j) tmp[j] = f2bf(W[(size_t)(k8 + j) * DD + n]);
  uint32_t w0 = (uint32_t)tmp[0] | ((uint32_t)tmp[1] << 16);
  uint32_t w1 = (uint32_t)tmp[2] | ((uint32_t)tmp[3] << 16);
  uint32_t w2 = (uint32_t)tmp[4] | ((uint32_t)tmp[5] << 16);
  uint32_t w3 = (uint32_t)tmp[6] | ((uint32_t)tmp[7] << 16);
  *(uint4*)&WT[(size_t)n * DD + k8] = make_uint4(w0, w1, w2, w3);
}

// ---------------------------------------------------------------- h = input @ W  (bf16 MFMA)
// R9->R10: occupancy fix — 64x128 tiles, 512 threads (8 waves, each 16 rows x 64 cols,
// acc=16 VGPR), grid (128,4)=512 blocks -> 2-4 blocks/CU (was 1 block/CU x 4 waves,
// latency-starved). Math bit-identical: same f2bf staging, same MFMA, same epilogue.
__global__ __launch_bounds__(512) void k_gemm_h(const float* __restrict__ Af,
                                                const u16* __restrict__ BT,
                                                u16* __restrict__ HT,
                                                const float* __restrict__ a1,
                                                const float* __restrict__ a2,
                                                float* __restrict__ e1part,
                                                float* __restrict__ e2part) {
  __shared__ __align__(16) u16 As[64 * 32];    // 4KB
  __shared__ __align__(16) u16 Bs[128 * 32];   // 8KB
  const int tid = threadIdx.x;
  const int wid = tid >> 6, lane = tid & 63;   // 8 waves
  const int wr = wid >> 1, wc = wid & 1;       // wave: rows wr*16, cols wc*64
  const int lr = lane & 15, kg = lane >> 4;
  const int rowBase = blockIdx.x * 64;
  const int colBase = blockIdx.y * 128;
  const int sr = tid >> 2, sc = tid & 3;       // staging coords
  f32x4_t acc[4] = {};
  for (int kt = 0; kt < 16; ++kt) {
    const int k0 = kt * 32 + sc * 8;
    if (tid < 256) {  // wave-uniform branch (waves 0..3): stage A rows 0..63
      float4 f0 = *(const float4*)&Af[(size_t)(rowBase + sr) * DD + k0];
      float4 f1 = *(const float4*)&Af[(size_t)(rowBase + sr) * DD + k0 + 4];
      *(uint4*)&As[sr * 32 + sc * 8] = make_uint4(
          (uint32_t)f2bf(f0.x) | ((uint32_t)f2bf(f0.y) << 16),
          (uint32_t)f2bf(f0.z) | ((uint32_t)f2bf(f0.w) << 16),
          (uint32_t)f2bf(f1.x) | ((uint32_t)f2bf(f1.y) << 16),
          (uint32_t)f2bf(f1.z) | ((uint32_t)f2bf(f1.w) << 16));
    }
    // all 512 threads: stage B rows 0..127
    *(uint4*)&Bs[sr * 32 + sc * 8] = *(const uint4*)&BT[(size_t)(colBase + sr) * DD + k0];
    __syncthreads();
    bf16x8_t af = *(const bf16x8_t*)&As[(wr * 16 + lr) * 32 + kg * 8];
    bf16x8_t bfv[4];
#pragma unroll
    for (int nt = 0; nt < 4; ++nt)
      bfv[nt] = *(const bf16x8_t*)&Bs[(wc * 64 + nt * 16 + lr) * 32 + kg * 8];
#pragma unroll
    for (int nt = 0; nt < 4; ++nt)
      acc[nt] = __builtin_amdgcn_mfma_f32_16x16x32_bf16(af, bfv[nt], acc[nt], 0, 0, 0);
    __syncthreads();
  }
  float a1v[4], a2v[4];
#pragma unroll
  for (int nt = 0; nt < 4; ++nt) {
    const int col = colBase + wc * 64 + nt * 16 + lr;
    a1v[nt] = a1[col];
    a2v[nt] = a2[col];
  }
  const int cg = blockIdx.y * 2 + wc;  // 64-col group 0..7
  const int row0 = rowBase + wr * 16 + kg * 4;
#pragma unroll
  for (int nt = 0; nt < 4; ++nt) {
    const int col = colBase + wc * 64 + nt * 16 + lr;
    uint32_t lo = (uint32_t)f2bf(acc[nt][0]) | ((uint32_t)f2bf(acc[nt][1]) << 16);
    uint32_t hi = (uint32_t)f2bf(acc[nt][2]) | ((uint32_t)f2bf(acc[nt][3]) << 16);
    *(uint2*)&HT[(size_t)col * NN + row0] = make_uint2(lo, hi);
  }
#pragma unroll
  for (int r = 0; r < 4; ++r) {
    float t1 = 0.f, t2 = 0.f;
#pragma unroll
    for (int nt = 0; nt < 4; ++nt) {
      t1 += acc[nt][r] * a1v[nt];
      t2 += acc[nt][r] * a2v[nt];
    }
#pragma unroll
    for (int m = 1; m <= 8; m <<= 1) {
      t1 += __shfl_xor(t1, m);
      t2 += __shfl_xor(t2, m);
    }
    if (lr == 0) {
      e1part[(size_t)cg * NN + row0 + r] = t1;
      e2part[(size_t)cg * NN + row0 + r] = t2;
    }
  }
}

// ---------------------------------------------------------------- reduce e1/e2 slices, maxE2
__global__ __launch_bounds__(256) void k_e12small(const float* __restrict__ e1part,
                                                  const float* __restrict__ e2part,
                                                  float* __restrict__ e1, float* __restrict__ e2,
                                                  unsigned* __restrict__ maxenc) {
  const int row = blockIdx.x * 256 + threadIdx.x;
  float s1 = 0.f, s2 = 0.f;
#pragma unroll
  for (int cg = 0; cg < 8; ++cg) {
    s1 += e1part[(size_t)cg * NN + row];
    s2 += e2part[(size_t)cg * NN + row];
  }
  e1[row] = s1;
  e2[row] = s2;
  atomicMax(maxenc, encf(s2));
}

// ---------------------------------------------------------------- fused masked-softmax @ h (split-K partials)
// R8 version verbatim (R9's cross-iteration pipeline spilled: WRITE 34->88MB, 115->186us).
// 256 blocks (XCD-swizzled, 1/CU) x 1024 threads. Block owns 128 rows x 2048 K-cols.
// B-fragments double-buffered in regs; numpart f16; P layout tau=tid (conflict-free).
__global__ __launch_bounds__(1024) void k_fused(const float* __restrict__ adj,
                                                const u16* __restrict__ HT,
                                                const float* __restrict__ e1,
                                                const float* __restrict__ e2,
                                                const unsigned* __restrict__ maxenc,
                                                u16* __restrict__ numpart,
                                                float* __restrict__ denpart) {
  __shared__ __align__(16) u16 P[2][128 * 128];       // 64KB double-buffered
  __shared__ __align__(16) float e2s[256 * 12];       // 12KB, stride-12 conflict-free
  __shared__ float partsum[2048];                     // 8KB
  const int tid = threadIdx.x;
  const int wid = tid >> 6;        // 0..15
  const int lane = tid & 63;
  const int lr = lane & 15;
  const int kg = lane >> 4;
  const int b = blockIdx.x;
  const int xcd = b & 7;
  const int bz = xcd >> 1;                           // 0..3, fixed per XCD
  const int rowBlock = (b >> 3) + ((xcd & 1) << 5);  // 0..63, bijective
  const int rowBase = rowBlock * 128;
  const int kk0 = bz * ITERS_PER_SPLIT;
  const int c = (tid >> 4) & 15;   // 8-col k-chunk within 128-tile
  const int m = tid & 15;
  const int mt0 = tid >> 8;        // 0..3
  const int r0l = mt0 * 16 + m;    // local rows r0l (0..63) and r0l+64
  const float e1r0 = e1[rowBase + r0l];
  const float e1r1 = e1[rowBase + r0l + 64];
  const float mE2 = decf(*maxenc);
  const float xb0 = e1r0 + mE2, xb1 = e1r1 + mE2;
  const float bnd0 = fmaxf(xb0, 0.2f * xb0);  // leakyrelu(e1+maxE2) >= all row scores
  const float bnd1 = fmaxf(xb1, 0.2f * xb1);
  {
    const float* e2g = e2 + kk0 * 128;
    if (tid < 256) {
      float4 u0 = *(const float4*)(e2g + tid * 8);
      float4 u1 = *(const float4*)(e2g + tid * 8 + 4);
      *(float4*)&e2s[tid * 12] = u0;
      *(float4*)&e2s[tid * 12 + 4] = u1;
    }
  }
  const float* adjp0 = adj + (size_t)(rowBase + r0l) * NN + c * 8;
  const float* adjp1 = adjp0 + (size_t)64 * NN;
  const int n0 = wid * 32;
  const u16* btp0 = HT + (size_t)(n0 + 0 + lr) * NN + kg * 8;
  const u16* btp1 = HT + (size_t)(n0 + 16 + lr) * NN + kg * 8;
  float dsum0 = 0.f, dsum1 = 0.f;
  f32x4_t acc[8][2] = {};
  f32x4_t a00 = __builtin_nontemporal_load((const f32x4_t*)(adjp0 + kk0 * 128));
  f32x4_t a01 = __builtin_nontemporal_load((const f32x4_t*)(adjp0 + kk0 * 128 + 4));
  f32x4_t a10 = __builtin_nontemporal_load((const f32x4_t*)(adjp1 + kk0 * 128));
  f32x4_t a11 = __builtin_nontemporal_load((const f32x4_t*)(adjp1 + kk0 * 128 + 4));
  __syncthreads();  // e2s ready
  for (int t = 0; t < ITERS_PER_SPLIT; ++t) {
    const int colBase = (kk0 + t) * 128;
    const float* eg = &e2s[(t * 16 + c) * 12];
    f32x4_t ev0 = *(const f32x4_t*)eg;
    f32x4_t ev1 = *(const f32x4_t*)(eg + 4);
    float ee[8] = {ev0[0], ev0[1], ev0[2], ev0[3], ev1[0], ev1[1], ev1[2], ev1[3]};
    float aa0[8] = {a00[0], a00[1], a00[2], a00[3], a01[0], a01[1], a01[2], a01[3]};
    float aa1[8] = {a10[0], a10[1], a10[2], a10[3], a11[0], a11[1], a11[2], a11[3]};
    float pv0[8], pv1[8];
#pragma unroll
    for (int j = 0; j < 8; ++j) {
      float x0 = e1r0 + ee[j];
      float s0 = fmaxf(x0, 0.2f * x0);
      float p0 = (aa0[j] > -1e19f) ? __expf(s0 - bnd0) : 0.f;
      pv0[j] = p0;
      dsum0 += p0;
      float x1 = e1r1 + ee[j];
      float s1 = fmaxf(x1, 0.2f * x1);
      float p1 = (aa1[j] > -1e19f) ? __expf(s1 - bnd1) : 0.f;
      pv1[j] = p1;
      dsum1 += p1;
    }
    {
      uint32_t w0 = (uint32_t)f2bf(pv0[0]) | ((uint32_t)f2bf(pv0[1]) << 16);
      uint32_t w1 = (uint32_t)f2bf(pv0[2]) | ((uint32_t)f2bf(pv0[3]) << 16);
      uint32_t w2 = (uint32_t)f2bf(pv0[4]) | ((uint32_t)f2bf(pv0[5]) << 16);
      uint32_t w3 = (uint32_t)f2bf(pv0[6]) | ((uint32_t)f2bf(pv0[7]) << 16);
      *(uint4*)&P[t & 1][tid * 8] = make_uint4(w0, w1, w2, w3);
      uint32_t v0 = (uint32_t)f2bf(pv1[0]) | ((uint32_t)f2bf(pv1[1]) << 16);
      uint32_t v1 = (uint32_t)f2bf(pv1[2]) | ((uint32_t)f2bf(pv1[3]) << 16);
      uint32_t v2 = (uint32_t)f2bf(pv1[4]) | ((uint32_t)f2bf(pv1[5]) << 16);
      uint32_t v3 = (uint32_t)f2bf(pv1[6]) | ((uint32_t)f2bf(pv1[7]) << 16);
      *(uint4*)&P[t & 1][(tid + 1024) * 8] = make_uint4(v0, v1, v2, v3);
    }
    if (t + 1 < ITERS_PER_SPLIT) {  // prefetch next iter adj; stays in flight across barrier
      const float* q0 = adjp0 + colBase + 128;
      const float* q1 = adjp1 + colBase + 128;
      a00 = __builtin_nontemporal_load((const f32x4_t*)q0);
      a01 = __builtin_nontemporal_load((const f32x4_t*)(q0 + 4));
      a10 = __builtin_nontemporal_load((const f32x4_t*)q1);
      a11 = __builtin_nontemporal_load((const f32x4_t*)(q1 + 4));
    }
    // preload ks=0 B-fragments (independent of P; in flight across barrier)
    bf16x8_t bc0 = *(const bf16x8_t*)(btp0 + colBase);
    bf16x8_t bc1 = *(const bf16x8_t*)(btp1 + colBase);
    asm volatile("s_waitcnt lgkmcnt(0)" ::: "memory");  // P writes visible; vmcnt NOT drained
    __builtin_amdgcn_s_barrier();
    const u16* pb = &P[t & 1][0];
#pragma unroll
    for (int ks = 0; ks < 4; ++ks) {
      bf16x8_t bn0, bn1;
      if (ks < 3) {  // double-buffer: issue next ks's B-loads before this ks's MFMAs
        const int co = colBase + (ks + 1) * 32;
        bn0 = *(const bf16x8_t*)(btp0 + co);
        bn1 = *(const bf16x8_t*)(btp1 + co);
      }
#pragma unroll
      for (int mt = 0; mt < 8; ++mt) {
        bf16x8_t af = *(const bf16x8_t*)(pb + mt * 2048 + ks * 512 + lane * 8);
        acc[mt][0] = __builtin_amdgcn_mfma_f32_16x16x32_bf16(af, bc0, acc[mt][0], 0, 0, 0);
        acc[mt][1] = __builtin_amdgcn_mfma_f32_16x16x32_bf16(af, bc1, acc[mt][1], 0, 0, 0);
      }
      if (ks < 3) { bc0 = bn0; bc1 = bn1; }
    }
  }
  // deterministic per-row denominator reduction (16 partials per row, fixed order)
  partsum[tid] = dsum0;
  partsum[tid + 1024] = dsum1;
  __syncthreads();
  if (tid < 128) {
    const int rr = tid;
    const int rlo = rr & 63;
    const int off = (rr >> 6) << 10;  // +1024 for rows 64..127
    float s = 0.f;
#pragma unroll
    for (int cc = 0; cc < 16; ++cc)
      s += partsum[off + (rlo >> 4) * 256 + cc * 16 + (rlo & 15)];
    denpart[(size_t)bz * NN + rowBase + rr] = s;
  }
  u16* np = numpart + (size_t)bz * NN * DD;
#pragma unroll
  for (int mt = 0; mt < 8; ++mt)
#pragma unroll
    for (int nt = 0; nt < 2; ++nt)
#pragma unroll
      for (int r = 0; r < 4; ++r) {
        const int rowL = mt * 16 + kg * 4 + r;
        _Float16 hv = (_Float16)acc[mt][nt][r];
        __builtin_nontemporal_store(__builtin_bit_cast(u16, hv),
                                    &np[(size_t)(rowBase + rowL) * DD + n0 + nt * 16 + lr]);
      }
}

// ---------------------------------------------------------------- combine f16 partials: out = tanh(num/den)
__global__ __launch_bounds__(256) void k_combine(const u16* __restrict__ num,
                                                 const float* __restrict__ den,
                                                 float* __restrict__ out) {
  const size_t idx = (size_t)blockIdx.x * 256 + threadIdx.x;  // 8-half units
  const int row = (int)(idx >> 6);                            // 64 chunks of 8 per row
  float d = den[row] + den[NN + row] + den[2 * NN + row] + den[3 * NN + row];
  const u32x4_t* nv = (const u32x4_t*)num;
  const size_t stride = (size_t)NN * DD / 8;
  float s[8] = {};
#pragma unroll
  for (int sl = 0; sl < 4; ++sl) {
    u32x4_t q = __builtin_nontemporal_load(nv + sl * stride + idx);
    s[0] += h2f(q[0] & 0xffff); s[1] += h2f(q[0] >> 16);
    s[2] += h2f(q[1] & 0xffff); s[3] += h2f(q[1] >> 16);
    s[4] += h2f(q[2] & 0xffff); s[5] += h2f(q[2] >> 16);
    s[6] += h2f(q[3] & 0xffff); s[7] += h2f(q[3] >> 16);
  }
  const float inv = (d > 0.f) ? 1.f / d : 0.f;
  f32x4_t o0, o1;
#pragma unroll
  for (int j = 0; j < 4; ++j) o0[j] = 1.f - 2.f / (__expf(2.f * (s[j] * inv)) + 1.f);
#pragma unroll
  for (int j = 0; j < 4; ++j) o1[j] = 1.f - 2.f / (__expf(2.f * (s[4 + j] * inv)) + 1.f);
  __builtin_nontemporal_store(o0, ((f32x4_t*)out) + idx * 2);
  __builtin_nontemporal_store(o1, ((f32x4_t*)out) + idx * 2 + 1);
}

// ----------------------------------------------------------------
extern "C" void kernel_launch(void* const* d_in, const int* in_sizes, int n_in,
                              void* d_out, int out_size, void* d_ws, size_t ws_size,
                              hipStream_t stream) {
  const float* input = (const float*)d_in[0];
  const float* adj   = (const float*)d_in[1];
  const float* W     = (const float*)d_in[2];
  const float* a1    = (const float*)d_in[3];
  const float* a2    = (const float*)d_in[4];
  float* out = (float*)d_out;
  char* ws = (char*)d_ws;

  u16* hT        = (u16*)ws;                      // 8192*512*2  = 8,388,608
  float* e1      = (float*)(ws + 8388608);        // 32,768
  float* e2      = (float*)(ws + 8421376);        // 32,768
  unsigned* mx   = (unsigned*)(ws + 8454144);     // 4 (pad to 256)
  float* denp    = (float*)(ws + 8454400);        // SPLIT*8192*4 = 131,072
  float* e1p     = (float*)(ws + 8585472);        // 8*8192*4 = 262,144
  float* e2p     = (float*)(ws + 8847616);        // 262,144
  u16* nump      = (u16*)(ws + 9109760);          // SPLIT*8192*512*2 = 33,554,432
  // WT is dead before k_fused writes nump -> overlay:
  u16* WT        = (u16*)(ws + 9109760);          // 524,288

  hipLaunchKernelGGL(k_convert_W, dim3(128), dim3(256), 0, stream, W, WT, mx);
  hipLaunchKernelGGL(k_gemm_h, dim3(128, 4), dim3(512), 0, stream, input, WT, hT, a1, a2, e1p, e2p);
  hipLaunchKernelGGL(k_e12small, dim3(32), dim3(256), 0, stream, e1p, e2p, e1, e2, mx);
  hipLaunchKernelGGL(k_fused, dim3(64 * SPLIT), dim3(1024), 0, stream, adj, hT, e1, e2, mx, nump, denp);
  hipLaunchKernelGGL(k_combine, dim3(2048), dim3(256), 0, stream, nump, denp, out);
}